// Round 2
// baseline (163497.485 us; speedup 1.0000x reference)
//
#include <hip/hip_runtime.h>
#include <math.h>

#define NB 256
#define NT 256

constexpr int B = 128, S = 512, D = 512, H = 512;
constexpr int G4 = 4 * H;  // 2048

__device__ __forceinline__ float sig(float x) { return 1.f / (1.f + expf(-x)); }

// Hierarchical grid barrier, normal launch. Safe without cooperative launch:
// 256 blocks x 4 waves, no LDS, low VGPR => all blocks provably co-resident
// (1024 waves << 8192 chip capacity). 8 group counters (64B apart) take 32
// arrivals each in parallel; last arriver of each group bumps root; everyone
// polls root. Monotone counters; round is 1-based barrier index.
__device__ __forceinline__ void gbar(unsigned* __restrict__ grp,
                                     unsigned* __restrict__ root,
                                     int g, unsigned round) {
  __syncthreads();
  if (threadIdx.x == 0) {
    unsigned old = __hip_atomic_fetch_add(&grp[g * 16], 1u, __ATOMIC_ACQ_REL,
                                          __HIP_MEMORY_SCOPE_AGENT);
    if (old + 1u == round * 32u)
      __hip_atomic_fetch_add(root, 1u, __ATOMIC_ACQ_REL,
                             __HIP_MEMORY_SCOPE_AGENT);
    while (__hip_atomic_load(root, __ATOMIC_ACQUIRE,
                             __HIP_MEMORY_SCOPE_AGENT) < round * 8u)
      __builtin_amdgcn_s_sleep(2);
  }
  __syncthreads();
}

// dot over K=512: a[k] (wave-uniform row -> scalar/broadcast loads) times
// weight column c (Wc[k*512], 64 consecutive c per wave -> 256B coalesced).
__device__ __forceinline__ float dot512(const float* __restrict__ a,
                                        const float* __restrict__ Wc) {
  float s0 = 0.f, s1 = 0.f, s2 = 0.f, s3 = 0.f;
#pragma unroll 4
  for (int k = 0; k < 512; k += 4) {
    s0 = fmaf(a[k + 0], Wc[(size_t)(k + 0) * 512], s0);
    s1 = fmaf(a[k + 1], Wc[(size_t)(k + 1) * 512], s1);
    s2 = fmaf(a[k + 2], Wc[(size_t)(k + 2) * 512], s2);
    s3 = fmaf(a[k + 3], Wc[(size_t)(k + 3) * 512], s3);
  }
  return (s0 + s1) + (s2 + s3);
}

__global__ void __launch_bounds__(NT) moglstm(
    const float* __restrict__ x, const float* __restrict__ Wih,
    const float* __restrict__ Whh, const float* __restrict__ bih,
    const float* __restrict__ bhh, const float* __restrict__ Qm,
    const float* __restrict__ Rm, float* __restrict__ out,
    float* __restrict__ ws) {
  float* h0 = ws;              // B*H, zeroed by host memset
  float* h1 = ws + B * H;      // B*H
  float* xm = ws + 2 * B * H;  // B*D
  unsigned* grp = (unsigned*)(ws + 3 * B * H);  // 8 counters, 64B apart
  unsigned* root = grp + 160;                   // own cacheline

  const int tid = threadIdx.x;
  const int blk = blockIdx.x;
  const int g = blk >> 5;  // barrier group, 32 blocks each

  // Block = 4 rows x 64 cols; each WAVE owns one full row => weight loads
  // are 64x4B=256B coalesced with no cross-wave redundancy on rows, and the
  // input row element a[k] is wave-uniform (broadcast/scalar load path).
  const int r = (blk >> 3) * 4 + (tid >> 6);  // 0..127
  const int c = (blk & 7) * 64 + (tid & 63);  // 0..511

  unsigned round = 0;
  float Creg = 0.f;  // cell state lives in a register for all 512 steps
  float* hc = h0;
  float* hn = h1;

  const float bi0 = bih[c] + bhh[c];
  const float bf0 = bih[H + c] + bhh[H + c];
  const float bg0 = bih[2 * H + c] + bhh[2 * H + c];
  const float bo0 = bih[3 * H + c] + bhh[3 * H + c];

  for (int t = 0; t < S; ++t) {
    const float* hr = hc + (size_t)r * H;
    const float* xr = xm + (size_t)r * D;
    const size_t rc_h = (size_t)r * H + c;

    // P0: xm = 2*sig(hc @ Q) * x_t
    {
      float d = dot512(hr, Qm + c);
      xm[(size_t)r * D + c] = 2.f * sig(d) * x[((size_t)r * S + t) * D + c];
    }
    gbar(grp, root, g, ++round);
    // P1: hc *= 2*sig(xm @ R)   (own element only)
    {
      float d = dot512(xr, Rm + c);
      hc[rc_h] *= 2.f * sig(d);
    }
    gbar(grp, root, g, ++round);
    // P2: xm *= 2*sig(hc @ Q)
    {
      float d = dot512(hr, Qm + c);
      xm[(size_t)r * D + c] *= 2.f * sig(d);
    }
    gbar(grp, root, g, ++round);
    // P3: hc *= 2*sig(xm @ R)
    {
      float d = dot512(xr, Rm + c);
      hc[rc_h] *= 2.f * sig(d);
    }
    gbar(grp, root, g, ++round);
    // P4: xm *= 2*sig(hc @ Q)
    {
      float d = dot512(hr, Qm + c);
      xm[(size_t)r * D + c] *= 2.f * sig(d);
    }
    gbar(grp, root, g, ++round);
    // P5: gates + LSTM pointwise (thread owns (r,c) and its 4 gate columns)
    {
      float ai = bi0, af = bf0, ag = bg0, ao = bo0;
      const float* wp = Wih + c;
#pragma unroll 2
      for (int k = 0; k < D; ++k) {
        float a = xr[k];
        ai = fmaf(a, wp[0], ai);
        af = fmaf(a, wp[H], af);
        ag = fmaf(a, wp[2 * H], ag);
        ao = fmaf(a, wp[3 * H], ao);
        wp += G4;
      }
      wp = Whh + c;
#pragma unroll 2
      for (int k = 0; k < H; ++k) {
        float a = hr[k];
        ai = fmaf(a, wp[0], ai);
        af = fmaf(a, wp[H], af);
        ag = fmaf(a, wp[2 * H], ag);
        ao = fmaf(a, wp[3 * H], ao);
        wp += G4;
      }
      float ft = sig(af), it = sig(ai), gt = tanhf(ag), ot = sig(ao);
      Creg = fmaf(ft, Creg, it * gt);
      float hv = ot * tanhf(Creg);
      hn[rc_h] = hv;
      out[((size_t)r * S + t) * H + c] = hv;
      if (t == S - 1) {
        out[(size_t)B * S * H + rc_h] = hv;
        out[(size_t)B * S * H + (size_t)B * H + rc_h] = Creg;
      }
    }
    gbar(grp, root, g, ++round);
    float* tt = hc; hc = hn; hn = tt;
  }
}

extern "C" void kernel_launch(void* const* d_in, const int* in_sizes, int n_in,
                              void* d_out, int out_size, void* d_ws, size_t ws_size,
                              hipStream_t stream) {
  const float* x   = (const float*)d_in[0];
  const float* Wih = (const float*)d_in[1];
  const float* Whh = (const float*)d_in[2];
  const float* bih = (const float*)d_in[3];
  const float* bhh = (const float*)d_in[4];
  const float* Qm  = (const float*)d_in[5];
  const float* Rm  = (const float*)d_in[6];
  float* out = (float*)d_out;
  float* ws  = (float*)d_ws;

  // ws is re-poisoned to 0xAA before every timed launch: zero h0 + barrier
  // counters (h1/xm are fully written before first read).
  hipMemsetAsync(d_ws, 0, (size_t)(3 * B * H) * sizeof(float) + 4096, stream);

  moglstm<<<dim3(NB), dim3(NT), 0, stream>>>(x, Wih, Whh, bih, bhh, Qm, Rm,
                                             out, ws);
}